// Round 11
// baseline (89.351 us; speedup 1.0000x reference)
//
#include <hip/hip_runtime.h>
#include <math.h>

#define KSTEPS 12
#define ITERS  4   // float4 elements per thread

typedef float f32x4 __attribute__((ext_vector_type(4)));

// ---- ordered-int <-> float bijection (monotone over finite floats) ----
__device__ __forceinline__ unsigned omap(float f) {
    unsigned u = __float_as_uint(f);
    return (u & 0x80000000u) ? ~u : (u | 0x80000000u);
}
__device__ __forceinline__ float ounmap(unsigned o) {
    unsigned bits = (o & 0x80000000u) ? (o ^ 0x80000000u) : ~o;
    return __uint_as_float(bits);
}

// Full 12-step decision mask for input x, using EXACTLY the arithmetic that
// measured absmax 0.0 vs numpy in rounds 1/3/4/6/8/9/10:
//   v = fmaf(-h,z,v)  (== round(v - z*h) since z in {0,1})
//   z = (v > T)       (== sign of (v-T)/(|v|+1), denominator > 0)
__device__ __forceinline__ int sim_mask(float x, const float* hh, const float* TT) {
    float v = x, zf = 0.f;
    int mask = 0;
#pragma unroll
    for (int t = 0; t < KSTEPS; ++t) {
        v  = fmaf(-hh[t], zf, v);
        zf = (v > TT[t]) ? 1.f : 0.f;
        mask |= (v > TT[t] ? 1 : 0) << t;
    }
    return mask;
}

// Setup (1 block, 64 threads; MUST stay a single block — R7 measured the
// per-block-redundant version at +4.3us of pure VALU): bisect the 12 fp-exact
// per-step thresholds (h<=0 => monotone in x => z_t = [x > theta_t]).
//   tbl[0..11]  : thresholds sorted ascending
//   tbl[12..24] : val[k] = fp-exact out value for k spikes, k packed into the
//                 low 4 mantissa bits (error <= 15 ulp ~ 1e-5 << 0.18 thresh)
// Also zeroes the two counters used by the fused finalize (runs first in the
// graph every replay -> replay-deterministic despite 0xAA ws poison).
__global__ void fsc_setup(const float* __restrict__ h, const float* __restrict__ d,
                          const float* __restrict__ T, float* __restrict__ tbl,
                          int* __restrict__ counters) {
    if (threadIdx.x < 2) counters[threadIdx.x] = 0;   // {spikeTotal, tickets}
    __shared__ float thRaw[KSTEPS];
    __shared__ int   rank[KSTEPS];
    float hh[KSTEPS], dd[KSTEPS], TT[KSTEPS];
#pragma unroll
    for (int t = 0; t < KSTEPS; ++t) { hh[t] = h[t]; dd[t] = d[t]; TT[t] = T[t]; }

    const int lane = threadIdx.x;
    if (lane < KSTEPS) {
        unsigned lo = omap(-128.0f), hi = omap(128.0f);
        float th;
        if (sim_mask(ounmap(lo), hh, TT) >> lane & 1)         th = -INFINITY;
        else if (!(sim_mask(ounmap(hi), hh, TT) >> lane & 1)) th = INFINITY;
        else {
            while (hi - lo > 1u) {
                unsigned mid = lo + (hi - lo) / 2u;
                if (sim_mask(ounmap(mid), hh, TT) >> lane & 1) hi = mid;
                else                                           lo = mid;
            }
            th = ounmap(lo);
        }
        thRaw[lane] = th;
    }
    __syncthreads();
    if (lane < KSTEPS) {
        const float th = thRaw[lane];
        int r = 0;
#pragma unroll
        for (int j = 0; j < KSTEPS; ++j) {
            const float oj = thRaw[j];
            if (oj < th || (oj == th && j < lane)) r++;
        }
        rank[lane] = r;
        tbl[r] = th;
    }
    __syncthreads();
    if (lane < KSTEPS + 1) {                // level k: spike at the k smallest
        float o = 0.f;
#pragma unroll
        for (int t = 0; t < KSTEPS; ++t) {
            const float zf = (rank[t] < lane) ? 1.f : 0.f;
            o = fmaf(dd[t], zf, o);         // fp-exact reference order
        }
        const unsigned b = (__float_as_uint(o) & ~15u) | (unsigned)lane;
        tbl[KSTEPS + lane] = __uint_as_float(b);
    }
}

// Main, ROUND-11 SINGLE CHANGE: fence-free fused finalize (2-node graph).
// R5's fused version was poisoned by __threadfence (per-block L2 flush);
// here ordering comes from a DATA dependency: the empty asm consumes the
// first atomic's return value, forcing the s_waitcnt vmcnt drain -- the add
// is visible at the coherence point once its response arrived -- before the
// ticket atomic issues. No fence, no flush, exact integer math.
__global__ __launch_bounds__(256) void fsc_main(
    const f32x4* __restrict__ x, const float* __restrict__ tbl,
    f32x4* __restrict__ out, int* __restrict__ counters,
    float* __restrict__ out_tail, double inv_n, int n4)
{
    const int tid    = blockIdx.x * blockDim.x + threadIdx.x;
    const int stride = gridDim.x * blockDim.x;
    int cnt = 0;

    float th[KSTEPS], val[KSTEPS + 1];
#pragma unroll
    for (int m = 0; m < KSTEPS; ++m) th[m] = tbl[m];        // uniform -> s_load
#pragma unroll
    for (int k = 0; k <= KSTEPS; ++k) val[k] = tbl[KSTEPS + k];

    if (tid + (ITERS - 1) * stride < n4) {  // fast path (grid divides exactly)
        f32x4 xv[ITERS];
#pragma unroll
        for (int u = 0; u < ITERS; ++u)
            xv[u] = __builtin_nontemporal_load(&x[tid + u * stride]);
#pragma unroll
        for (int u = 0; u < ITERS; ++u) {
            f32x4 ov;
#pragma unroll
            for (int j = 0; j < 4; ++j) {
                const float xj = xv[u][j];
                float e = val[0];
#pragma unroll
                for (int m = 0; m < KSTEPS; ++m)
                    e = (xj > th[m]) ? val[m + 1] : e;
                ov[j] = e;
                cnt += (int)(__float_as_uint(e) & 15u);
            }
            __builtin_nontemporal_store(ov, &out[tid + u * stride]);
        }
    } else {
        for (int i = tid; i < n4; i += stride) {
            const f32x4 xv = __builtin_nontemporal_load(&x[i]);
            f32x4 ov;
#pragma unroll
            for (int j = 0; j < 4; ++j) {
                const float xj = xv[j];
                float e = val[0];
#pragma unroll
                for (int m = 0; m < KSTEPS; ++m)
                    e = (xj > th[m]) ? val[m + 1] : e;
                ov[j] = e;
                cnt += (int)(__float_as_uint(e) & 15u);
            }
            __builtin_nontemporal_store(ov, &out[i]);
        }
    }

    // block reduce (wave shfl -> LDS), then fence-free fused finalize
    const int lane = threadIdx.x & 63;
    const int wv   = threadIdx.x >> 6;
    __shared__ int smi[4];
#pragma unroll
    for (int off = 32; off > 0; off >>= 1) cnt += __shfl_down(cnt, off);
    if (lane == 0) smi[wv] = cnt;
    __syncthreads();
    if (threadIdx.x == 0) {
        const int blockCnt = smi[0] + smi[1] + smi[2] + smi[3];   // <= 49152
        const int old0 = atomicAdd(&counters[0], blockCnt);       // total <= 154M
        asm volatile("" :: "v"(old0));   // wait for the add's response (visible)
        const int ticket = atomicAdd(&counters[1], 1);
        if (ticket == (int)gridDim.x - 1) {   // every block's c[0] add landed
            const int tot = atomicAdd(&counters[0], 0);           // exact total
            out_tail[0] = 0.0f;               // v_reg: analytically zero (|T|<1)
            out_tail[1] = (float)((double)tot * inv_n);           // z_reg
        }
    }
}

extern "C" void kernel_launch(void* const* d_in, const int* in_sizes, int n_in,
                              void* d_out, int out_size, void* d_ws, size_t ws_size,
                              hipStream_t stream) {
    const f32x4*  x    = (const f32x4*)d_in[0];
    const float*  h    = (const float*)d_in[1];
    const float*  dpar = (const float*)d_in[2];
    const float*  T    = (const float*)d_in[3];
    float* out = (float*)d_out;

    const int n  = in_sizes[0];   // 12,845,056
    const int n4 = n / 4;         // 3,211,264 = 3136 * 256 * 4 exactly
    const int blocks = (n4 + 256 * ITERS - 1) / (256 * ITERS);

    float* tbl      = (float*)d_ws;               // 25 floats
    int*   counters = (int*)((char*)d_ws + 256);  // {spikeTotal, tickets}

    fsc_setup<<<1,      64,  0, stream>>>(h, dpar, T, tbl, counters);
    fsc_main <<<blocks, 256, 0, stream>>>(x, tbl, (f32x4*)out, counters,
                                          out + n, 1.0 / (double)n, n4);
}

// Round 12
// 33.582 us; speedup vs baseline: 2.6606x; 2.6606x over previous
//
#include <hip/hip_runtime.h>
#include <math.h>

#define KSTEPS 12

typedef float f32x4 __attribute__((ext_vector_type(4)));

// ---- ordered-int <-> float bijection (monotone over finite floats) ----
__device__ __forceinline__ unsigned omap(float f) {
    unsigned u = __float_as_uint(f);
    return (u & 0x80000000u) ? ~u : (u | 0x80000000u);
}
__device__ __forceinline__ float ounmap(unsigned o) {
    unsigned bits = (o & 0x80000000u) ? (o ^ 0x80000000u) : ~o;
    return __uint_as_float(bits);
}

// Full 12-step decision mask for input x, using EXACTLY the arithmetic that
// measured absmax 0.0 vs numpy in rounds 1/3/4/6/8/9/10/11:
//   v = fmaf(-h,z,v)  (== round(v - z*h) since z in {0,1})
//   z = (v > T)       (== sign of (v-T)/(|v|+1), denominator > 0)
__device__ __forceinline__ int sim_mask(float x, const float* hh, const float* TT) {
    float v = x, zf = 0.f;
    int mask = 0;
#pragma unroll
    for (int t = 0; t < KSTEPS; ++t) {
        v  = fmaf(-hh[t], zf, v);
        zf = (v > TT[t]) ? 1.f : 0.f;
        mask |= (v > TT[t] ? 1 : 0) << t;
    }
    return mask;
}

// Setup (1 block, 64 threads; MUST stay single-block — R7 measured the
// per-block-redundant version at +4.3us pure VALU). Bisects the 12 fp-exact
// per-step thresholds (h<=0 => monotone in x => z_t = [x > theta_t]).
//   tbl[0..11]  : thresholds sorted ascending
//   tbl[12..24] : val[k] = fp-exact out value for k spikes, k packed into the
//                 low 4 mantissa bits (error <= 15 ulp ~ 1e-5 << 0.18 thresh)
__global__ void fsc_setup(const float* __restrict__ h, const float* __restrict__ d,
                          const float* __restrict__ T, float* __restrict__ tbl) {
    __shared__ float thRaw[KSTEPS];
    __shared__ int   rank[KSTEPS];
    float hh[KSTEPS], dd[KSTEPS], TT[KSTEPS];
#pragma unroll
    for (int t = 0; t < KSTEPS; ++t) { hh[t] = h[t]; dd[t] = d[t]; TT[t] = T[t]; }

    const int lane = threadIdx.x;
    if (lane < KSTEPS) {
        unsigned lo = omap(-128.0f), hi = omap(128.0f);
        float th;
        if (sim_mask(ounmap(lo), hh, TT) >> lane & 1)         th = -INFINITY;
        else if (!(sim_mask(ounmap(hi), hh, TT) >> lane & 1)) th = INFINITY;
        else {
            while (hi - lo > 1u) {
                unsigned mid = lo + (hi - lo) / 2u;
                if (sim_mask(ounmap(mid), hh, TT) >> lane & 1) hi = mid;
                else                                           lo = mid;
            }
            th = ounmap(lo);
        }
        thRaw[lane] = th;
    }
    __syncthreads();
    if (lane < KSTEPS) {
        const float th = thRaw[lane];
        int r = 0;
#pragma unroll
        for (int j = 0; j < KSTEPS; ++j) {
            const float oj = thRaw[j];
            if (oj < th || (oj == th && j < lane)) r++;
        }
        rank[lane] = r;
        tbl[r] = th;
    }
    __syncthreads();
    if (lane < KSTEPS + 1) {                // level k: spike at the k smallest
        float o = 0.f;
#pragma unroll
        for (int t = 0; t < KSTEPS; ++t) {
            const float zf = (rank[t] < lane) ? 1.f : 0.f;
            o = fmaf(dd[t], zf, o);         // fp-exact reference order
        }
        const unsigned b = (__float_as_uint(o) & ~15u) | (unsigned)lane;
        tbl[KSTEPS + lane] = __uint_as_float(b);
    }
}

// Main, ROUND-12 SINGLE CHANGE: software-pipelined grid-stride loop.
// R4/R6/R8/R10 all plateau at ~35us total with upfront-burst loads: each
// wave alternates a load burst with a ~1664-cycle pure-VALU stretch, so the
// CU's memory pipe idles during compute (VALU 12.5us + mem 16us ~ serialize).
// Here every iteration prefetches the NEXT float4 before computing the
// current one (1 load + 1 store in flight per iter, m13-copy style), so the
// memory stream runs continuously and VALU hides underneath it.
// 1792 blocks x 256 threads x exactly 7 iterations = n4.
__global__ __launch_bounds__(256) void fsc_main(
    const f32x4* __restrict__ x, const float* __restrict__ tbl,
    f32x4* __restrict__ out, float* __restrict__ partial, int n4)
{
    const int tid    = blockIdx.x * blockDim.x + threadIdx.x;
    const int stride = gridDim.x * blockDim.x;
    int cnt = 0;

    float th[KSTEPS], val[KSTEPS + 1];
#pragma unroll
    for (int m = 0; m < KSTEPS; ++m) th[m] = tbl[m];        // uniform -> s_load
#pragma unroll
    for (int k = 0; k <= KSTEPS; ++k) val[k] = tbl[KSTEPS + k];

    if (tid < n4) {
        f32x4 cur = __builtin_nontemporal_load(&x[tid]);
        int i = tid, nxt_i = tid + stride;
        while (nxt_i < n4) {
            const f32x4 nxt = __builtin_nontemporal_load(&x[nxt_i]);  // prefetch
            f32x4 ov;
#pragma unroll
            for (int j = 0; j < 4; ++j) {
                const float xj = cur[j];
                float e = val[0];
#pragma unroll
                for (int m = 0; m < KSTEPS; ++m)
                    e = (xj > th[m]) ? val[m + 1] : e;
                ov[j] = e;
                cnt += (int)(__float_as_uint(e) & 15u);
            }
            __builtin_nontemporal_store(ov, &out[i]);
            cur = nxt; i = nxt_i; nxt_i += stride;
        }
        {   // last iteration
            f32x4 ov;
#pragma unroll
            for (int j = 0; j < 4; ++j) {
                const float xj = cur[j];
                float e = val[0];
#pragma unroll
                for (int m = 0; m < KSTEPS; ++m)
                    e = (xj > th[m]) ? val[m + 1] : e;
                ov[j] = e;
                cnt += (int)(__float_as_uint(e) & 15u);
            }
            __builtin_nontemporal_store(ov, &out[i]);
        }
    }

    // spike-count reduce: wave shfl -> LDS -> one exact float per block
    const int lane = threadIdx.x & 63;
    const int wv   = threadIdx.x >> 6;
    __shared__ int smi[4];
#pragma unroll
    for (int off = 32; off > 0; off >>= 1) cnt += __shfl_down(cnt, off);
    if (lane == 0) smi[wv] = cnt;
    __syncthreads();
    if (threadIdx.x == 0)
        partial[blockIdx.x] = (float)(smi[0] + smi[1] + smi[2] + smi[3]);  // exact int
}

__global__ __launch_bounds__(256) void fsc_finalize(
    const float* __restrict__ partial, int nblocks,
    float* __restrict__ out_tail, double inv_n)
{
    double acc = 0.0;
    for (int b = threadIdx.x; b < nblocks; b += blockDim.x)
        acc += (double)partial[b];
    const int lane = threadIdx.x & 63;
    const int wv   = threadIdx.x >> 6;
    __shared__ double sm[4];
#pragma unroll
    for (int off = 32; off > 0; off >>= 1) acc += __shfl_down(acc, off);
    if (lane == 0) sm[wv] = acc;
    __syncthreads();
    if (threadIdx.x == 0) {
        const double tot = sm[0] + sm[1] + sm[2] + sm[3];   // exact integer
        out_tail[0] = 0.0f;                  // v_reg: analytically zero (|T|<1)
        out_tail[1] = (float)(tot * inv_n);  // z_reg
    }
}

extern "C" void kernel_launch(void* const* d_in, const int* in_sizes, int n_in,
                              void* d_out, int out_size, void* d_ws, size_t ws_size,
                              hipStream_t stream) {
    const f32x4*  x    = (const f32x4*)d_in[0];
    const float*  h    = (const float*)d_in[1];
    const float*  dpar = (const float*)d_in[2];
    const float*  T    = (const float*)d_in[3];
    float* out = (float*)d_out;

    const int n  = in_sizes[0];   // 12,845,056
    const int n4 = n / 4;         // 3,211,264 = 1792 * 256 * 7 exactly
    const int blocks = 1792;      // 7 blocks/CU, 7 pipelined iters/thread

    float* tbl     = (float*)d_ws;        // 25 floats
    float* partial = (float*)d_ws + 64;   // `blocks` floats

    fsc_setup   <<<1,      64,  0, stream>>>(h, dpar, T, tbl);
    fsc_main    <<<blocks, 256, 0, stream>>>(x, tbl, (f32x4*)out, partial, n4);
    fsc_finalize<<<1,      256, 0, stream>>>(partial, blocks, out + n, 1.0 / (double)n);
}